// Round 16
// baseline (317.344 us; speedup 1.0000x reference)
//
#include <hip/hip_runtime.h>
#include <hip/hip_bf16.h>
#include <cstdint>
#include <cstddef>

// ---------------------------------------------------------------------------
// MGCN (2-layer relational GCN + linear head).
//
//   s_in[v]  = norm[v] * sum_{first-half edges,  dst=v} x[src]*rel[ty]
//   s_out[v] = norm[v] * sum_{second-half edges, dst=v} x[src]*rel[ty]
//   h        = x + res * tanh( x@W_loop + s_in@W_in + s_out@W_out + b )
//   out      = h2 @ mu_w + mu_b     (fused into layer-2 kernel)
//
// R15 + 32-ROW GEMM TILES: grid 1563 (~6.1 blocks/CU) to kill the CU
// load-imbalance tail that pinned the 64-row version (782 = 3x256+14 ->
// 4L vs 3L per-CU work quantization).  All fp8 paths unchanged.
// ---------------------------------------------------------------------------

typedef short bf16x8 __attribute__((ext_vector_type(8)));
typedef float f32x4  __attribute__((ext_vector_type(4)));
typedef float f32x2  __attribute__((ext_vector_type(2)));

__device__ __forceinline__ float b2f(unsigned short u) {
    union { unsigned u32; float f; } c; c.u32 = ((unsigned)u) << 16; return c.f;
}
__device__ __forceinline__ unsigned short f2b(float f) {
    union { float f; unsigned u; } c; c.f = f;
    unsigned r = c.u + 0x7FFFu + ((c.u >> 16) & 1u);   // RNE
    return (unsigned short)(r >> 16);
}
__device__ __forceinline__ float ftanh(float x) {
    float e = __expf(2.0f * x);
    return 1.0f - __fdividef(2.0f, e + 1.0f);
}

// f32 -> fp8 e4m3fn (OCP), RNE, saturating (software fallback).
__device__ __forceinline__ unsigned char f2e4m3(float f) {
    unsigned u = __float_as_uint(f);
    unsigned s = (u >> 24) & 0x80u;
    unsigned a = u & 0x7fffffffu;
    if (a >= 0x43e00000u) return (unsigned char)(s | 0x7eu);
    if (a < 0x3c800000u) {
        float m = __uint_as_float(a) * 512.0f;
        int q = (int)rintf(m);
        if (q == 8) return (unsigned char)(s | 0x08u);
        return (unsigned char)(s | (unsigned)q);
    }
    unsigned m = a & 0x7fffffu;
    unsigned e = a >> 23;
    unsigned r = m + 0x7ffffu + ((m >> 20) & 1u);
    if (r >= 0x800000u) { e += 1; r -= 0x800000u; }
    if (e > 127u + 8u) return (unsigned char)(s | 0x7eu);
    return (unsigned char)(s | ((e - 127u + 7u) << 3) | (r >> 20));
}

__device__ __forceinline__ unsigned pk8_4(float a, float b, float c, float d) {
#if __has_builtin(__builtin_amdgcn_cvt_pk_fp8_f32)
    int v = 0;
    v = __builtin_amdgcn_cvt_pk_fp8_f32(a, b, v, false);
    v = __builtin_amdgcn_cvt_pk_fp8_f32(c, d, v, true);
    return (unsigned)v;
#else
    return (unsigned)f2e4m3(a) | ((unsigned)f2e4m3(b) << 8)
         | ((unsigned)f2e4m3(c) << 16) | ((unsigned)f2e4m3(d) << 24);
#endif
}

__device__ __forceinline__ void dec4(unsigned u, float* f) {
#if __has_builtin(__builtin_amdgcn_cvt_pk_f32_fp8)
    f32x2 lo = __builtin_amdgcn_cvt_pk_f32_fp8((int)u, false);
    f32x2 hi = __builtin_amdgcn_cvt_pk_f32_fp8((int)u, true);
    f[0] = lo[0]; f[1] = lo[1]; f[2] = hi[0]; f[3] = hi[1];
#else
    #pragma unroll
    for (int i = 0; i < 4; ++i) {
        unsigned b = (u >> (8 * i)) & 0xffu;
        unsigned em = b & 0x7fu;
        float mag;
        if (em >= 8u) mag = __uint_as_float((((em >> 3) + 120u) << 23) | ((em & 7u) << 20));
        else          mag = (float)em * 0.001953125f;
        f[i] = (b & 0x80u) ? -mag : mag;
    }
#endif
}

// ---- CSR construction ------------------------------------------------------

__global__ void k_hist(const int* __restrict__ dst, int* __restrict__ cnt, int E) {
    int i = blockIdx.x * blockDim.x + threadIdx.x;
    if (i < E) atomicAdd(&cnt[dst[i]], 1);
}

__global__ void k_norm(const int* __restrict__ cnt, float* __restrict__ norm, int N) {
    int i = blockIdx.x * blockDim.x + threadIdx.x;
    if (i < N) norm[i] = 1.0f / fmaxf((float)cnt[i], 1.0f);
}

__global__ void k_scan1(const int* __restrict__ cnt, int* __restrict__ part,
                        int* __restrict__ bsum, int N) {
    __shared__ int s[256];
    int i = blockIdx.x * 256 + threadIdx.x;
    int v = (i < N) ? cnt[i] : 0;
    s[threadIdx.x] = v; __syncthreads();
    #pragma unroll
    for (int o = 1; o < 256; o <<= 1) {
        int t = (threadIdx.x >= o) ? s[threadIdx.x - o] : 0;
        __syncthreads();
        s[threadIdx.x] += t;
        __syncthreads();
    }
    if (i < N) part[i] = s[threadIdx.x] - v;
    if (threadIdx.x == 255) bsum[blockIdx.x] = s[255];
}

__global__ void k_scan2(int* __restrict__ bsum, int nb) {
    __shared__ int s[256];
    int v = (threadIdx.x < nb) ? bsum[threadIdx.x] : 0;
    s[threadIdx.x] = v; __syncthreads();
    #pragma unroll
    for (int o = 1; o < 256; o <<= 1) {
        int t = (threadIdx.x >= o) ? s[threadIdx.x - o] : 0;
        __syncthreads();
        s[threadIdx.x] += t;
        __syncthreads();
    }
    if (threadIdx.x < nb) bsum[threadIdx.x] = s[threadIdx.x] - v;
}

__global__ void k_scan3(const int* __restrict__ part, const int* __restrict__ bsum,
                        int* __restrict__ rowptr, int* __restrict__ cursor, int N, int E) {
    int i = blockIdx.x * 256 + threadIdx.x;
    if (i < N) {
        int r = part[i] + bsum[blockIdx.x];
        rowptr[i] = r; cursor[i] = r;
    }
    if (i == 0) rowptr[N] = E;
}

__global__ void k_scatter(const int* __restrict__ src, const int* __restrict__ dst,
                          const int* __restrict__ et, int* __restrict__ cursor,
                          unsigned* __restrict__ erec, int E, int halfE) {
    int e = blockIdx.x * blockDim.x + threadIdx.x;
    if (e < E) {
        int d = dst[e];
        int pos = atomicAdd(&cursor[d], 1);
        unsigned rec = (unsigned)src[e] | ((unsigned)et[e] << 16)
                     | ((e >= halfE) ? 0x80000000u : 0u);
        erec[pos] = rec;
    }
}

// ---- dtype prep ------------------------------------------------------------

__global__ void k_cvtx3(const float* __restrict__ s0, unsigned short* __restrict__ d0,
                        unsigned char* __restrict__ e0, long n0,
                        const float* __restrict__ s1, unsigned short* __restrict__ d1,
                        unsigned char* __restrict__ e1, long n1,
                        const float* __restrict__ s2, unsigned short* __restrict__ d2,
                        unsigned char* __restrict__ e2, long n2) {
    long i = (long)blockIdx.x * blockDim.x + threadIdx.x;
    const float* s; unsigned short* d; unsigned char* e; long j = i;
    if (j < n0) { s = s0; d = d0; e = e0; }
    else {
        j -= n0;
        if (j < n1) { s = s1; d = d1; e = e1; }
        else { j -= n1; if (j >= n2) return; s = s2; d = d2; e = e2; }
    }
    float4 v = ((const float4*)s)[j];
    ushort4 o;
    o.x = f2b(v.x); o.y = f2b(v.y); o.z = f2b(v.z); o.w = f2b(v.w);
    ((ushort4*)d)[j] = o;
    ((unsigned*)e)[j] = pk8_4(v.x, v.y, v.z, v.w);
}

// bf16 fragment table: mu_w only
__global__ void k_wfrag1(const float* __restrict__ W, unsigned short* __restrict__ out) {
    int o = blockIdx.x * 256 + threadIdx.x;
    int j  = o & 7;
    int l  = (o >> 3) & 63;
    int nn = (o >> 9) & 15;
    int kg = o >> 13;
    int k = kg * 32 + (l >> 4) * 8 + j;
    int n = nn * 16 + (l & 15);
    out[o] = f2b(W[k * 256 + n]);
}

// fp8 fragment tables: Wl1, Wi1, Wo1, Wl2, Wi2, Wo2 (8-byte frags)
__global__ void k_wfrag8(const float* __restrict__ w0, const float* __restrict__ w1,
                         const float* __restrict__ w2, const float* __restrict__ w3,
                         const float* __restrict__ w4, const float* __restrict__ w5,
                         unsigned char* __restrict__ out) {
    int o = (blockIdx.x * 256 + threadIdx.x) * 4;
    int mi = o >> 16;
    int r  = o & 65535;
    const float* W = (mi == 0) ? w0 : (mi == 1) ? w1 : (mi == 2) ? w2 :
                     (mi == 3) ? w3 : (mi == 4) ? w4 : w5;
    int j0 = r & 7;
    int l  = (r >> 3) & 63;
    int nn = (r >> 9) & 15;
    int kg = r >> 13;
    int n  = nn * 16 + (l & 15);
    int kb = kg * 32 + (l >> 4) * 8 + j0;
    *(unsigned*)(out + o) = pk8_4(W[(kb + 0) * 256 + n], W[(kb + 1) * 256 + n],
                                  W[(kb + 2) * 256 + n], W[(kb + 3) * 256 + n]);
}

// ---- CSR gather aggregation: fp8 in/out, 4-edge pipeline (R14, verified) ---

__global__ __launch_bounds__(256)
void k_agg(const unsigned char* __restrict__ x8, const unsigned char* __restrict__ rel8,
           const int* __restrict__ rowptr, const unsigned* __restrict__ erec,
           const float* __restrict__ norm,
           unsigned char* __restrict__ sIn8, unsigned char* __restrict__ sOut8,
           int N, int D)
{
    const int w = threadIdx.x >> 6, l = threadIdx.x & 63;
    const int v = blockIdx.x * 4 + w;
    if (v >= N) return;
    const int rs = rowptr[v], re = rowptr[v + 1];
    const float nm = norm[v];

    float ai0 = 0, ai1 = 0, ai2 = 0, ai3 = 0;
    float ao0 = 0, ao1 = 0, ao2 = 0, ao3 = 0;

    unsigned c0 = (rs     < re) ? erec[rs]     : 0u;
    unsigned c1 = (rs + 1 < re) ? erec[rs + 1] : 0u;
    unsigned c2 = (rs + 2 < re) ? erec[rs + 2] : 0u;
    unsigned c3 = (rs + 3 < re) ? erec[rs + 3] : 0u;
    int i = rs;
    while (i + 4 <= re) {
        unsigned m0 = (i + 4 < re) ? erec[i + 4] : 0u;
        unsigned m1 = (i + 5 < re) ? erec[i + 5] : 0u;
        unsigned m2 = (i + 6 < re) ? erec[i + 6] : 0u;
        unsigned m3 = (i + 7 < re) ? erec[i + 7] : 0u;
        unsigned xu0 = *(const unsigned*)(x8   + (size_t)(c0 & 0xffff) * 256 + l * 4);
        unsigned ru0 = *(const unsigned*)(rel8 + (size_t)((c0 >> 16) & 0x7fff) * 256 + l * 4);
        unsigned xu1 = *(const unsigned*)(x8   + (size_t)(c1 & 0xffff) * 256 + l * 4);
        unsigned ru1 = *(const unsigned*)(rel8 + (size_t)((c1 >> 16) & 0x7fff) * 256 + l * 4);
        unsigned xu2 = *(const unsigned*)(x8   + (size_t)(c2 & 0xffff) * 256 + l * 4);
        unsigned ru2 = *(const unsigned*)(rel8 + (size_t)((c2 >> 16) & 0x7fff) * 256 + l * 4);
        unsigned xu3 = *(const unsigned*)(x8   + (size_t)(c3 & 0xffff) * 256 + l * 4);
        unsigned ru3 = *(const unsigned*)(rel8 + (size_t)((c3 >> 16) & 0x7fff) * 256 + l * 4);
        float xf[4], rf[4];
        dec4(xu0, xf); dec4(ru0, rf);
        if (c0 >> 31) { ao0 += xf[0]*rf[0]; ao1 += xf[1]*rf[1]; ao2 += xf[2]*rf[2]; ao3 += xf[3]*rf[3]; }
        else          { ai0 += xf[0]*rf[0]; ai1 += xf[1]*rf[1]; ai2 += xf[2]*rf[2]; ai3 += xf[3]*rf[3]; }
        dec4(xu1, xf); dec4(ru1, rf);
        if (c1 >> 31) { ao0 += xf[0]*rf[0]; ao1 += xf[1]*rf[1]; ao2 += xf[2]*rf[2]; ao3 += xf[3]*rf[3]; }
        else          { ai0 += xf[0]*rf[0]; ai1 += xf[1]*rf[1]; ai2 += xf[2]*rf[2]; ai3 += xf[3]*rf[3]; }
        dec4(xu2, xf); dec4(ru2, rf);
        if (c2 >> 31) { ao0 += xf[0]*rf[0]; ao1 += xf[1]*rf[1]; ao2 += xf[2]*rf[2]; ao3 += xf[3]*rf[3]; }
        else          { ai0 += xf[0]*rf[0]; ai1 += xf[1]*rf[1]; ai2 += xf[2]*rf[2]; ai3 += xf[3]*rf[3]; }
        dec4(xu3, xf); dec4(ru3, rf);
        if (c3 >> 31) { ao0 += xf[0]*rf[0]; ao1 += xf[1]*rf[1]; ao2 += xf[2]*rf[2]; ao3 += xf[3]*rf[3]; }
        else          { ai0 += xf[0]*rf[0]; ai1 += xf[1]*rf[1]; ai2 += xf[2]*rf[2]; ai3 += xf[3]*rf[3]; }
        c0 = m0; c1 = m1; c2 = m2; c3 = m3; i += 4;
    }
    #pragma unroll
    for (int j = 0; j < 3; ++j) {
        if (i + j < re) {
            unsigned cur = (j == 0) ? c0 : (j == 1) ? c1 : c2;
            unsigned xu = *(const unsigned*)(x8   + (size_t)(cur & 0xffff) * 256 + l * 4);
            unsigned ru = *(const unsigned*)(rel8 + (size_t)((cur >> 16) & 0x7fff) * 256 + l * 4);
            float xf[4], rf[4];
            dec4(xu, xf); dec4(ru, rf);
            if (cur >> 31) { ao0 += xf[0]*rf[0]; ao1 += xf[1]*rf[1]; ao2 += xf[2]*rf[2]; ao3 += xf[3]*rf[3]; }
            else           { ai0 += xf[0]*rf[0]; ai1 += xf[1]*rf[1]; ai2 += xf[2]*rf[2]; ai3 += xf[3]*rf[3]; }
        }
    }

    *(unsigned*)(sIn8  + (size_t)v * 256 + l * 4) = pk8_4(ai0 * nm, ai1 * nm, ai2 * nm, ai3 * nm);
    *(unsigned*)(sOut8 + (size_t)v * 256 + l * 4) = pk8_4(ao0 * nm, ao1 * nm, ao2 * nm, ao3 * nm);
}

// ---- all-fp8 GEMM: 32-row tiles, uniform 12-step pipeline ------------------
// Staging by threads 0..127 (one 16B chunk each: 32 rows x 4 chunks).

#define FB  do { asm volatile("s_waitcnt lgkmcnt(0)" ::: "memory");             \
                 __builtin_amdgcn_sched_barrier(0);                             \
                 __builtin_amdgcn_s_barrier();                                  \
                 __builtin_amdgcn_sched_barrier(0); } while (0)

#define WR8(AtN, R0)     do { if (t < 128) *(uint4*)((AtN) + wf8b) = R0; } while (0)
#define LD8(R0, SRC, CB) do { if (t < 128) R0 = *(const uint4*)((SRC) + gf8 + (CB)*64); } while (0)

#define PB8(Bn, TBL, CB)                                                        \
  do { _Pragma("unroll")                                                        \
       for (int kk_ = 0; kk_ < 2; ++kk_) {                                      \
         _Pragma("unroll")                                                      \
         for (int n_ = 0; n_ < 4; ++n_)                                         \
           Bn[kk_*4+n_] = *(const long long*)((TBL) +                           \
               ((((CB)*2+kk_)*16 + (w*4+n_))*64 + l)*8);                        \
       } } while (0)

#define MM8(AtC, Bc)                                                            \
  do { const char* A8_ = (const char*)(AtC);                                    \
       _Pragma("unroll")                                                        \
       for (int kk_ = 0; kk_ < 2; ++kk_) {                                      \
         long long a_[2];                                                       \
         _Pragma("unroll")                                                      \
         for (int m_ = 0; m_ < 2; ++m_) {                                       \
           int rm_ = 16*m_ + lr; int ch_ = (kk_*4+lq) ^ (rm_ & 6);              \
           a_[m_] = *(const long long*)(A8_ + rm_*64 + ch_*8);                  \
         }                                                                      \
         _Pragma("unroll")                                                      \
         for (int m_ = 0; m_ < 2; ++m_) {                                       \
           _Pragma("unroll")                                                    \
           for (int n_ = 0; n_ < 4; ++n_)                                       \
             acc[m_][n_] = __builtin_amdgcn_mfma_f32_16x16x32_fp8_fp8(          \
                 a_[m_], Bc[kk_*4+n_], acc[m_][n_], 0, 0, 0);                   \
         } } } while (0)

template <bool HEAD>
__global__ __launch_bounds__(256, 6)
void k_gemm(const unsigned char*  __restrict__ a8,     // [N,256] fp8 x / h1 (A op)
            const unsigned short* __restrict__ ares,   // [N,256] bf16 residual
            const unsigned char*  __restrict__ s8i,    // [N,256] fp8 sIn
            const unsigned char*  __restrict__ s8o,    // [N,256] fp8 sOut
            const unsigned char*  __restrict__ W8L,    // fp8 frag (W_loop)
            const unsigned char*  __restrict__ W8I,    // fp8 frag (W_in)
            const unsigned char*  __restrict__ W8O,    // fp8 frag (W_out)
            const float* __restrict__ bias,
            const float* __restrict__ resPtr,
            const unsigned short* __restrict__ WfMu,   // bf16 frag (HEAD)
            const float* __restrict__ mub,             // (HEAD)
            float* __restrict__ outF,                  // (HEAD)
            unsigned short* __restrict__ outB,         // (!HEAD)
            unsigned char* __restrict__ outB8,         // (!HEAD) fp8 h copy
            int N, int D)
{
    __shared__ unsigned char ldsb[HEAD ? 16384 : 8192];
    unsigned char* At0 = ldsb;
    unsigned char* At1 = ldsb + 2048;

    const int t = threadIdx.x;
    const int rBase = blockIdx.x * 32;

    const int w  = t >> 6;
    const int l  = t & 63;
    const int lr = l & 15;
    const int lq = l >> 4;

    // fp8 staging geometry (threads 0..127: one 16B chunk each)
    const int rf  = (t & 127) >> 2;              // 0..31
    const int qf  = t & 3;
    const int wf8b = rf * 64 + (((2 * qf) ^ (rf & 6)) * 8);
    const size_t gf8 = (size_t)min(rBase + rf, N - 1) * 256 + qf * 16;

    f32x4 acc[2][4] = {};
    uint4 Ra, Rb, Rc, Rd, Re, Rf;
    long long B8a[8], B8b[8];

    // prologue: tiles 0..5 in flight; tile0 -> At0; B(step0)
    LD8(Ra, a8, 0); LD8(Rb, a8, 1); LD8(Rc, a8, 2); LD8(Rd, a8, 3);
    LD8(Re, s8i, 0); LD8(Rf, s8i, 1);
    PB8(B8a, W8L, 0);
    WR8(At0, Ra);
    FB;

    /*s0 */ WR8(At1, Rb); PB8(B8b, W8L, 1); MM8(At0, B8a); LD8(Ra, s8i, 2); FB;
    /*s1 */ WR8(At0, Rc); PB8(B8a, W8L, 2); MM8(At1, B8b); LD8(Rb, s8i, 3); FB;
    /*s2 */ WR8(At1, Rd); PB8(B8b, W8L, 3); MM8(At0, B8a); LD8(Rc, s8o, 0); FB;
    /*s3 */ WR8(At0, Re); PB8(B8a, W8I, 0); MM8(At1, B8b); LD8(Rd, s8o, 1); FB;
    /*s4 */ WR8(At1, Rf); PB8(B8b, W8I, 1); MM8(At0, B8a); LD8(Re, s8o, 2); FB;
    /*s5 */ WR8(At0, Ra); PB8(B8a, W8I, 2); MM8(At1, B8b); LD8(Rf, s8o, 3); FB;
    /*s6 */ WR8(At1, Rb); PB8(B8b, W8I, 3); MM8(At0, B8a); FB;
    /*s7 */ WR8(At0, Rc); PB8(B8a, W8O, 0); MM8(At1, B8b); FB;
    /*s8 */ WR8(At1, Rd); PB8(B8b, W8O, 1); MM8(At0, B8a); FB;
    /*s9 */ WR8(At0, Re); PB8(B8a, W8O, 2); MM8(At1, B8b); FB;
    /*s10*/ WR8(At1, Rf); PB8(B8b, W8O, 3); MM8(At0, B8a); FB;
    /*s11*/                                 MM8(At1, B8b); FB;

    const int rb4 = lq * 4;
    const float resv = resPtr[0];

    if (!HEAD) {
        // ---- coalesced epilogue: stage res*tanh(acc+bias) in LDS halves ----
        unsigned short* C = (unsigned short*)ldsb;   // 32 x 128 bf16 per half
        #pragma unroll
        for (int half = 0; half < 2; ++half) {
            if ((w >> 1) == half) {
                #pragma unroll
                for (int m = 0; m < 2; ++m) {
                    #pragma unroll
                    for (int i = 0; i < 4; ++i) {
                        int r6 = 16 * m + rb4 + i;
                        #pragma unroll
                        for (int n = 0; n < 4; ++n) {
                            int cH = (w & 1) * 64 + lr + 16 * n;
                            float v = acc[m][n][i] + bias[half * 128 + cH];
                            C[r6 * 128 + cH] = f2b(resv * ftanh(v));
                        }
                    }
                }
            }
            __syncthreads();
            #pragma unroll
            for (int ii = 0; ii < 2; ++ii) {
                int g   = ii * 256 + t;              // 512 chunks total
                int r   = g >> 4;                    // 0..31
                int cc  = g & 15;
                int row = rBase + r;
                if (row < N) {
                    bf16x8 sv = *(const bf16x8*)(&C[r * 128 + cc * 8]);
                    const unsigned short* ar = ares + (size_t)row * D + half * 128 + cc * 8;
                    uint4 av = *(const uint4*)ar;
                    unsigned aw[4] = { av.x, av.y, av.z, av.w };
                    unsigned ow[4];
                    float hv[8];
                    #pragma unroll
                    for (int p = 0; p < 4; ++p) {
                        float h0 = b2f((unsigned short)(aw[p] & 0xffff)) + b2f((unsigned short)sv[2 * p]);
                        float h1 = b2f((unsigned short)(aw[p] >> 16))    + b2f((unsigned short)sv[2 * p + 1]);
                        hv[2 * p] = h0; hv[2 * p + 1] = h1;
                        ow[p] = (unsigned)f2b(h0) | ((unsigned)f2b(h1) << 16);
                    }
                    *(uint4*)(outB + (size_t)row * D + half * 128 + cc * 8) =
                        make_uint4(ow[0], ow[1], ow[2], ow[3]);
                    uint2 q;
                    q.x = pk8_4(hv[0], hv[1], hv[2], hv[3]);
                    q.y = pk8_4(hv[4], hv[5], hv[6], hv[7]);
                    *(uint2*)(outB8 + (size_t)row * 256 + half * 128 + cc * 8) = q;
                }
            }
            __syncthreads();
        }
    } else {
        // ---- HEAD: h2 -> swizzled LDS bf16 tile, then out = h2 @ WfMu + mub ----
        unsigned short* lds = (unsigned short*)ldsb;   // 32 x 256 bf16 = 16 KB
        #pragma unroll
        for (int m = 0; m < 2; ++m) {
            #pragma unroll
            for (int i = 0; i < 4; ++i) {
                int row = rBase + 16 * m + rb4 + i;
                if (row < N) {
                    size_t base = (size_t)row * D + w * 64 + lr;
                    int r6 = 16 * m + rb4 + i;
                    #pragma unroll
                    for (int n = 0; n < 4; ++n) {
                        int   c = w * 64 + lr + 16 * n;
                        float v = acc[m][n][i] + bias[c];
                        float h = b2f(ares[base + 16 * n]) + resv * ftanh(v);
                        lds[r6 * 256 + (c ^ ((r6 & 7) << 3))] = f2b(h);
                    }
                }
            }
        }
        __syncthreads();
        #pragma unroll
        for (int m = 0; m < 2; ++m) {
            #pragma unroll
            for (int n = 0; n < 4; ++n)
                acc[m][n] = (f32x4){0.f, 0.f, 0.f, 0.f};
        }

        #pragma unroll
        for (int s2 = 0; s2 < 4; ++s2) {
            #pragma unroll
            for (int kk = 0; kk < 2; ++kk) {
                const int kg = s2 * 2 + kk;
                bf16x8 a_[2], b_[4];
                #pragma unroll
                for (int m = 0; m < 2; ++m) {
                    int rm = 16 * m + lr;
                    int ch = (s2 * 8 + kk * 4 + lq) ^ (rm & 7);
                    a_[m] = *(const bf16x8*)(&lds[rm * 256 + ch * 8]);
                }
                #pragma unroll
                for (int n = 0; n < 4; ++n)
                    b_[n] = *(const bf16x8*)(WfMu + (((kg * 16 + (w * 4 + n)) * 64 + l) * 8));
                #pragma unroll
                for (int m = 0; m < 2; ++m) {
                    #pragma unroll
                    for (int n = 0; n < 4; ++n)
                        acc[m][n] = __builtin_amdgcn_mfma_f32_16x16x32_bf16(a_[m], b_[n], acc[m][n], 0, 0, 0);
                }
            }
        }

        __syncthreads();
        float* Cf = (float*)ldsb;                     // 32 x 128 f32 per half
        #pragma unroll
        for (int half = 0; half < 2; ++half) {
            if ((w >> 1) == half) {
                #pragma unroll
                for (int m = 0; m < 2; ++m) {
                    #pragma unroll
                    for (int i = 0; i < 4; ++i) {
                        int r6 = 16 * m + rb4 + i;
                        #pragma unroll
                        for (int n = 0; n < 4; ++n) {
                            int cH = (w & 1) * 64 + lr + 16 * n;
                            Cf[r6 * 128 + cH] = acc[m][n][i] + mub[half * 128 + cH];
                        }
                    }
                }
            }
            __syncthreads();
            #pragma unroll
            for (int ii = 0; ii < 4; ++ii) {
                int g   = ii * 256 + t;               // 1024 float4-chunks total
                int r   = g >> 5;                     // 0..31
                int cc  = g & 31;
                int row = rBase + r;
                if (row < N) {
                    *(float4*)(outF + (size_t)row * D + half * 128 + cc * 4) =
                        *(const float4*)(&Cf[r * 128 + cc * 4]);
                }
            }
            __syncthreads();
        }
    }
}

// ---------------------------------------------------------------------------

extern "C" void kernel_launch(void* const* d_in, const int* in_sizes, int n_in,
                              void* d_out, int out_size, void* d_ws, size_t ws_size,
                              hipStream_t stream)
{
    const float* emb  = (const float*)d_in[0];
    const int*   ei   = (const int*)  d_in[1];
    const int*   et   = (const int*)  d_in[2];
    const float* rel1 = (const float*)d_in[3];
    const float* Wi1  = (const float*)d_in[4];
    const float* Wo1  = (const float*)d_in[5];
    const float* Wl1  = (const float*)d_in[6];
    const float* b1   = (const float*)d_in[7];
    const float* rel2 = (const float*)d_in[8];
    const float* Wi2  = (const float*)d_in[9];
    const float* Wo2  = (const float*)d_in[10];
    const float* Wl2  = (const float*)d_in[11];
    const float* b2   = (const float*)d_in[12];
    const float* res  = (const float*)d_in[13];
    const float* muw  = (const float*)d_in[14];
    const float* mub  = (const float*)d_in[15];

    const int D = in_sizes[7];          // 256
    const int N = in_sizes[0] / D;      // 50000
    const int E = in_sizes[2];          // 320000
    const int R = in_sizes[3] / D;      // 400
    const int halfE = E / 2;
    const int* srcA = ei;
    const int* dstA = ei + E;
    const size_t DD = (size_t)D * D;

    char* ws = (char*)d_ws;
    size_t off = 0;
    auto alloc = [&](size_t bytes) -> char* {
        char* p = ws + off; off += (bytes + 255) & ~(size_t)255; return p;
    };
    const int nb1 = (N + 255) / 256;

    float*          norm   = (float*)          alloc((size_t)N * 4);
    int*            cnt    = (int*)            alloc((size_t)N * 4);
    int*            rowptr = (int*)            alloc((size_t)(N + 1) * 4);
    int*            cursor = (int*)            alloc((size_t)N * 4);
    int*            part   = (int*)            alloc((size_t)N * 4);
    int*            bsum   = (int*)            alloc(1024);
    unsigned*       erec   = (unsigned*)       alloc((size_t)E * 4);
    unsigned short* xb     = (unsigned short*) alloc((size_t)N * D * 2);
    unsigned short* h1b    = (unsigned short*) alloc((size_t)N * D * 2);
    unsigned char*  x8     = (unsigned char*)  alloc((size_t)N * D);
    unsigned char*  h18    = (unsigned char*)  alloc((size_t)N * D);
    unsigned char*  sIn8   = (unsigned char*)  alloc((size_t)N * D);
    unsigned char*  sOut8  = (unsigned char*)  alloc((size_t)N * D);
    unsigned short* r1b    = (unsigned short*) alloc((size_t)R * D * 2);
    unsigned short* r2b    = (unsigned short*) alloc((size_t)R * D * 2);
    unsigned char*  r18    = (unsigned char*)  alloc((size_t)R * D);
    unsigned char*  r28    = (unsigned char*)  alloc((size_t)R * D);
    unsigned short* fMu    = (unsigned short*) alloc(DD * 2);
    unsigned char*  f8All  = (unsigned char*)  alloc(6 * DD);
    if (off > ws_size) return;

    unsigned char* f8Wl1 = f8All;
    unsigned char* f8Wi1 = f8All + DD;
    unsigned char* f8Wo1 = f8All + 2 * DD;
    unsigned char* f8Wl2 = f8All + 3 * DD;
    unsigned char* f8Wi2 = f8All + 4 * DD;
    unsigned char* f8Wo2 = f8All + 5 * DD;

    // --- CSR + norm ---
    hipMemsetAsync(cnt, 0, (size_t)N * 4, stream);
    k_hist   <<<(E + 255) / 256, 256, 0, stream>>>(dstA, cnt, E);
    k_norm   <<<nb1, 256, 0, stream>>>(cnt, norm, N);
    k_scan1  <<<nb1, 256, 0, stream>>>(cnt, part, bsum, N);
    k_scan2  <<<1,   256, 0, stream>>>(bsum, nb1);
    k_scan3  <<<nb1, 256, 0, stream>>>(part, bsum, rowptr, cursor, N, E);
    k_scatter<<<(E + 255) / 256, 256, 0, stream>>>(srcA, dstA, et, cursor, erec, E, halfE);

    // --- dtype prep ---
    long nd4 = (long)N * D / 4, rd4 = (long)R * D / 4;
    long tot4 = nd4 + 2 * rd4;
    k_cvtx3<<<(int)((tot4 + 255) / 256), 256, 0, stream>>>(
        emb, xb, x8, nd4, rel1, r1b, r18, rd4, rel2, r2b, r28, rd4);
    k_wfrag1<<<(int)(DD / 256), 256, 0, stream>>>(muw, fMu);
    k_wfrag8<<<(int)(6 * DD / 1024), 256, 0, stream>>>(Wl1, Wi1, Wo1, Wl2, Wi2, Wo2, f8All);

    const int AB = (N + 3) / 4;
    const int NB = (N + 31) / 32;     // 32-row GEMM tiles

    // --- layer 1 ---
    k_agg<<<AB, 256, 0, stream>>>(x8, r18, rowptr, erec, norm, sIn8, sOut8, N, D);
    k_gemm<false><<<NB, 256, 0, stream>>>(x8, xb, sIn8, sOut8, f8Wl1, f8Wi1, f8Wo1, b1, res,
                                          nullptr, nullptr, nullptr, h1b, h18, N, D);

    // --- layer 2 + head ---
    k_agg<<<AB, 256, 0, stream>>>(h18, r28, rowptr, erec, norm, sIn8, sOut8, N, D);
    k_gemm<true><<<NB, 256, 0, stream>>>(h18, h1b, sIn8, sOut8, f8Wl2, f8Wi2, f8Wo2, b2, res,
                                         fMu, mub, (float*)d_out, nullptr, nullptr, N, D);
}

// Round 17
// 205.397 us; speedup vs baseline: 1.5450x; 1.5450x over previous
//
#include <hip/hip_runtime.h>
#include <hip/hip_bf16.h>
#include <cstdint>
#include <cstddef>

// ---------------------------------------------------------------------------
// MGCN (2-layer relational GCN + linear head).  R15 configuration (best).
//
//   s_in[v]  = norm[v] * sum_{first-half edges,  dst=v} x[src]*rel[ty]
//   s_out[v] = norm[v] * sum_{second-half edges, dst=v} x[src]*rel[ty]
//   h        = x + res * tanh( x@W_loop + s_in@W_in + s_out@W_out + b )
//   out      = h2 @ mu_w + mu_b     (fused into layer-2 kernel)
//
// fp8 everywhere on the streaming paths: gather reads fp8 x/rel copies,
// s_in/s_out stored fp8, GEMM A-operands and W tables fp8
// (mfma_f32_16x16x32_fp8_fp8), 64-row tiles, 12-step barrier pipeline with
// 6-deep register A prefetch.  Residual path bf16; head GEMM bf16.
// ---------------------------------------------------------------------------

typedef short bf16x8 __attribute__((ext_vector_type(8)));
typedef float f32x4  __attribute__((ext_vector_type(4)));
typedef float f32x2  __attribute__((ext_vector_type(2)));

__device__ __forceinline__ float b2f(unsigned short u) {
    union { unsigned u32; float f; } c; c.u32 = ((unsigned)u) << 16; return c.f;
}
__device__ __forceinline__ unsigned short f2b(float f) {
    union { float f; unsigned u; } c; c.f = f;
    unsigned r = c.u + 0x7FFFu + ((c.u >> 16) & 1u);   // RNE
    return (unsigned short)(r >> 16);
}
__device__ __forceinline__ float ftanh(float x) {
    float e = __expf(2.0f * x);
    return 1.0f - __fdividef(2.0f, e + 1.0f);
}

// f32 -> fp8 e4m3fn (OCP), RNE, saturating (software fallback).
__device__ __forceinline__ unsigned char f2e4m3(float f) {
    unsigned u = __float_as_uint(f);
    unsigned s = (u >> 24) & 0x80u;
    unsigned a = u & 0x7fffffffu;
    if (a >= 0x43e00000u) return (unsigned char)(s | 0x7eu);
    if (a < 0x3c800000u) {
        float m = __uint_as_float(a) * 512.0f;
        int q = (int)rintf(m);
        if (q == 8) return (unsigned char)(s | 0x08u);
        return (unsigned char)(s | (unsigned)q);
    }
    unsigned m = a & 0x7fffffu;
    unsigned e = a >> 23;
    unsigned r = m + 0x7ffffu + ((m >> 20) & 1u);
    if (r >= 0x800000u) { e += 1; r -= 0x800000u; }
    if (e > 127u + 8u) return (unsigned char)(s | 0x7eu);
    return (unsigned char)(s | ((e - 127u + 7u) << 3) | (r >> 20));
}

__device__ __forceinline__ unsigned pk8_4(float a, float b, float c, float d) {
#if __has_builtin(__builtin_amdgcn_cvt_pk_fp8_f32)
    int v = 0;
    v = __builtin_amdgcn_cvt_pk_fp8_f32(a, b, v, false);
    v = __builtin_amdgcn_cvt_pk_fp8_f32(c, d, v, true);
    return (unsigned)v;
#else
    return (unsigned)f2e4m3(a) | ((unsigned)f2e4m3(b) << 8)
         | ((unsigned)f2e4m3(c) << 16) | ((unsigned)f2e4m3(d) << 24);
#endif
}

__device__ __forceinline__ void dec4(unsigned u, float* f) {
#if __has_builtin(__builtin_amdgcn_cvt_pk_f32_fp8)
    f32x2 lo = __builtin_amdgcn_cvt_pk_f32_fp8((int)u, false);
    f32x2 hi = __builtin_amdgcn_cvt_pk_f32_fp8((int)u, true);
    f[0] = lo[0]; f[1] = lo[1]; f[2] = hi[0]; f[3] = hi[1];
#else
    #pragma unroll
    for (int i = 0; i < 4; ++i) {
        unsigned b = (u >> (8 * i)) & 0xffu;
        unsigned em = b & 0x7fu;
        float mag;
        if (em >= 8u) mag = __uint_as_float((((em >> 3) + 120u) << 23) | ((em & 7u) << 20));
        else          mag = (float)em * 0.001953125f;
        f[i] = (b & 0x80u) ? -mag : mag;
    }
#endif
}

// ---- CSR construction ------------------------------------------------------

__global__ void k_hist(const int* __restrict__ dst, int* __restrict__ cnt, int E) {
    int i = blockIdx.x * blockDim.x + threadIdx.x;
    if (i < E) atomicAdd(&cnt[dst[i]], 1);
}

__global__ void k_norm(const int* __restrict__ cnt, float* __restrict__ norm, int N) {
    int i = blockIdx.x * blockDim.x + threadIdx.x;
    if (i < N) norm[i] = 1.0f / fmaxf((float)cnt[i], 1.0f);
}

__global__ void k_scan1(const int* __restrict__ cnt, int* __restrict__ part,
                        int* __restrict__ bsum, int N) {
    __shared__ int s[256];
    int i = blockIdx.x * 256 + threadIdx.x;
    int v = (i < N) ? cnt[i] : 0;
    s[threadIdx.x] = v; __syncthreads();
    #pragma unroll
    for (int o = 1; o < 256; o <<= 1) {
        int t = (threadIdx.x >= o) ? s[threadIdx.x - o] : 0;
        __syncthreads();
        s[threadIdx.x] += t;
        __syncthreads();
    }
    if (i < N) part[i] = s[threadIdx.x] - v;
    if (threadIdx.x == 255) bsum[blockIdx.x] = s[255];
}

__global__ void k_scan2(int* __restrict__ bsum, int nb) {
    __shared__ int s[256];
    int v = (threadIdx.x < nb) ? bsum[threadIdx.x] : 0;
    s[threadIdx.x] = v; __syncthreads();
    #pragma unroll
    for (int o = 1; o < 256; o <<= 1) {
        int t = (threadIdx.x >= o) ? s[threadIdx.x - o] : 0;
        __syncthreads();
        s[threadIdx.x] += t;
        __syncthreads();
    }
    if (threadIdx.x < nb) bsum[threadIdx.x] = s[threadIdx.x] - v;
}

__global__ void k_scan3(const int* __restrict__ part, const int* __restrict__ bsum,
                        int* __restrict__ rowptr, int* __restrict__ cursor, int N, int E) {
    int i = blockIdx.x * 256 + threadIdx.x;
    if (i < N) {
        int r = part[i] + bsum[blockIdx.x];
        rowptr[i] = r; cursor[i] = r;
    }
    if (i == 0) rowptr[N] = E;
}

__global__ void k_scatter(const int* __restrict__ src, const int* __restrict__ dst,
                          const int* __restrict__ et, int* __restrict__ cursor,
                          unsigned* __restrict__ erec, int E, int halfE) {
    int e = blockIdx.x * blockDim.x + threadIdx.x;
    if (e < E) {
        int d = dst[e];
        int pos = atomicAdd(&cursor[d], 1);
        unsigned rec = (unsigned)src[e] | ((unsigned)et[e] << 16)
                     | ((e >= halfE) ? 0x80000000u : 0u);
        erec[pos] = rec;
    }
}

// ---- dtype prep ------------------------------------------------------------

__global__ void k_cvtx3(const float* __restrict__ s0, unsigned short* __restrict__ d0,
                        unsigned char* __restrict__ e0, long n0,
                        const float* __restrict__ s1, unsigned short* __restrict__ d1,
                        unsigned char* __restrict__ e1, long n1,
                        const float* __restrict__ s2, unsigned short* __restrict__ d2,
                        unsigned char* __restrict__ e2, long n2) {
    long i = (long)blockIdx.x * blockDim.x + threadIdx.x;
    const float* s; unsigned short* d; unsigned char* e; long j = i;
    if (j < n0) { s = s0; d = d0; e = e0; }
    else {
        j -= n0;
        if (j < n1) { s = s1; d = d1; e = e1; }
        else { j -= n1; if (j >= n2) return; s = s2; d = d2; e = e2; }
    }
    float4 v = ((const float4*)s)[j];
    ushort4 o;
    o.x = f2b(v.x); o.y = f2b(v.y); o.z = f2b(v.z); o.w = f2b(v.w);
    ((ushort4*)d)[j] = o;
    ((unsigned*)e)[j] = pk8_4(v.x, v.y, v.z, v.w);
}

// bf16 fragment table: mu_w only
__global__ void k_wfrag1(const float* __restrict__ W, unsigned short* __restrict__ out) {
    int o = blockIdx.x * 256 + threadIdx.x;
    int j  = o & 7;
    int l  = (o >> 3) & 63;
    int nn = (o >> 9) & 15;
    int kg = o >> 13;
    int k = kg * 32 + (l >> 4) * 8 + j;
    int n = nn * 16 + (l & 15);
    out[o] = f2b(W[k * 256 + n]);
}

// fp8 fragment tables: Wl1, Wi1, Wo1, Wl2, Wi2, Wo2 (8-byte frags)
__global__ void k_wfrag8(const float* __restrict__ w0, const float* __restrict__ w1,
                         const float* __restrict__ w2, const float* __restrict__ w3,
                         const float* __restrict__ w4, const float* __restrict__ w5,
                         unsigned char* __restrict__ out) {
    int o = (blockIdx.x * 256 + threadIdx.x) * 4;
    int mi = o >> 16;
    int r  = o & 65535;
    const float* W = (mi == 0) ? w0 : (mi == 1) ? w1 : (mi == 2) ? w2 :
                     (mi == 3) ? w3 : (mi == 4) ? w4 : w5;
    int j0 = r & 7;
    int l  = (r >> 3) & 63;
    int nn = (r >> 9) & 15;
    int kg = r >> 13;
    int n  = nn * 16 + (l & 15);
    int kb = kg * 32 + (l >> 4) * 8 + j0;
    *(unsigned*)(out + o) = pk8_4(W[(kb + 0) * 256 + n], W[(kb + 1) * 256 + n],
                                  W[(kb + 2) * 256 + n], W[(kb + 3) * 256 + n]);
}

// ---- CSR gather aggregation: fp8 in/out, 4-edge pipeline -------------------

__global__ __launch_bounds__(256)
void k_agg(const unsigned char* __restrict__ x8, const unsigned char* __restrict__ rel8,
           const int* __restrict__ rowptr, const unsigned* __restrict__ erec,
           const float* __restrict__ norm,
           unsigned char* __restrict__ sIn8, unsigned char* __restrict__ sOut8,
           int N, int D)
{
    const int w = threadIdx.x >> 6, l = threadIdx.x & 63;
    const int v = blockIdx.x * 4 + w;
    if (v >= N) return;
    const int rs = rowptr[v], re = rowptr[v + 1];
    const float nm = norm[v];

    float ai0 = 0, ai1 = 0, ai2 = 0, ai3 = 0;
    float ao0 = 0, ao1 = 0, ao2 = 0, ao3 = 0;

    unsigned c0 = (rs     < re) ? erec[rs]     : 0u;
    unsigned c1 = (rs + 1 < re) ? erec[rs + 1] : 0u;
    unsigned c2 = (rs + 2 < re) ? erec[rs + 2] : 0u;
    unsigned c3 = (rs + 3 < re) ? erec[rs + 3] : 0u;
    int i = rs;
    while (i + 4 <= re) {
        unsigned m0 = (i + 4 < re) ? erec[i + 4] : 0u;
        unsigned m1 = (i + 5 < re) ? erec[i + 5] : 0u;
        unsigned m2 = (i + 6 < re) ? erec[i + 6] : 0u;
        unsigned m3 = (i + 7 < re) ? erec[i + 7] : 0u;
        unsigned xu0 = *(const unsigned*)(x8   + (size_t)(c0 & 0xffff) * 256 + l * 4);
        unsigned ru0 = *(const unsigned*)(rel8 + (size_t)((c0 >> 16) & 0x7fff) * 256 + l * 4);
        unsigned xu1 = *(const unsigned*)(x8   + (size_t)(c1 & 0xffff) * 256 + l * 4);
        unsigned ru1 = *(const unsigned*)(rel8 + (size_t)((c1 >> 16) & 0x7fff) * 256 + l * 4);
        unsigned xu2 = *(const unsigned*)(x8   + (size_t)(c2 & 0xffff) * 256 + l * 4);
        unsigned ru2 = *(const unsigned*)(rel8 + (size_t)((c2 >> 16) & 0x7fff) * 256 + l * 4);
        unsigned xu3 = *(const unsigned*)(x8   + (size_t)(c3 & 0xffff) * 256 + l * 4);
        unsigned ru3 = *(const unsigned*)(rel8 + (size_t)((c3 >> 16) & 0x7fff) * 256 + l * 4);
        float xf[4], rf[4];
        dec4(xu0, xf); dec4(ru0, rf);
        if (c0 >> 31) { ao0 += xf[0]*rf[0]; ao1 += xf[1]*rf[1]; ao2 += xf[2]*rf[2]; ao3 += xf[3]*rf[3]; }
        else          { ai0 += xf[0]*rf[0]; ai1 += xf[1]*rf[1]; ai2 += xf[2]*rf[2]; ai3 += xf[3]*rf[3]; }
        dec4(xu1, xf); dec4(ru1, rf);
        if (c1 >> 31) { ao0 += xf[0]*rf[0]; ao1 += xf[1]*rf[1]; ao2 += xf[2]*rf[2]; ao3 += xf[3]*rf[3]; }
        else          { ai0 += xf[0]*rf[0]; ai1 += xf[1]*rf[1]; ai2 += xf[2]*rf[2]; ai3 += xf[3]*rf[3]; }
        dec4(xu2, xf); dec4(ru2, rf);
        if (c2 >> 31) { ao0 += xf[0]*rf[0]; ao1 += xf[1]*rf[1]; ao2 += xf[2]*rf[2]; ao3 += xf[3]*rf[3]; }
        else          { ai0 += xf[0]*rf[0]; ai1 += xf[1]*rf[1]; ai2 += xf[2]*rf[2]; ai3 += xf[3]*rf[3]; }
        dec4(xu3, xf); dec4(ru3, rf);
        if (c3 >> 31) { ao0 += xf[0]*rf[0]; ao1 += xf[1]*rf[1]; ao2 += xf[2]*rf[2]; ao3 += xf[3]*rf[3]; }
        else          { ai0 += xf[0]*rf[0]; ai1 += xf[1]*rf[1]; ai2 += xf[2]*rf[2]; ai3 += xf[3]*rf[3]; }
        c0 = m0; c1 = m1; c2 = m2; c3 = m3; i += 4;
    }
    #pragma unroll
    for (int j = 0; j < 3; ++j) {
        if (i + j < re) {
            unsigned cur = (j == 0) ? c0 : (j == 1) ? c1 : c2;
            unsigned xu = *(const unsigned*)(x8   + (size_t)(cur & 0xffff) * 256 + l * 4);
            unsigned ru = *(const unsigned*)(rel8 + (size_t)((cur >> 16) & 0x7fff) * 256 + l * 4);
            float xf[4], rf[4];
            dec4(xu, xf); dec4(ru, rf);
            if (cur >> 31) { ao0 += xf[0]*rf[0]; ao1 += xf[1]*rf[1]; ao2 += xf[2]*rf[2]; ao3 += xf[3]*rf[3]; }
            else           { ai0 += xf[0]*rf[0]; ai1 += xf[1]*rf[1]; ai2 += xf[2]*rf[2]; ai3 += xf[3]*rf[3]; }
        }
    }

    *(unsigned*)(sIn8  + (size_t)v * 256 + l * 4) = pk8_4(ai0 * nm, ai1 * nm, ai2 * nm, ai3 * nm);
    *(unsigned*)(sOut8 + (size_t)v * 256 + l * 4) = pk8_4(ao0 * nm, ao1 * nm, ao2 * nm, ao3 * nm);
}

// ---- all-fp8 GEMM: 64-row tiles, uniform 12-step pipeline ------------------

#define FB  do { asm volatile("s_waitcnt lgkmcnt(0)" ::: "memory");             \
                 __builtin_amdgcn_sched_barrier(0);                             \
                 __builtin_amdgcn_s_barrier();                                  \
                 __builtin_amdgcn_sched_barrier(0); } while (0)

#define WR8(AtN, R0)     do { *(uint4*)((AtN) + wf8b) = R0; } while (0)
#define LD8(R0, SRC, CB) do { R0 = *(const uint4*)((SRC) + gf8 + (CB)*64); } while (0)

#define PB8(Bn, TBL, CB)                                                        \
  do { _Pragma("unroll")                                                        \
       for (int kk_ = 0; kk_ < 2; ++kk_) {                                      \
         _Pragma("unroll")                                                      \
         for (int n_ = 0; n_ < 4; ++n_)                                         \
           Bn[kk_*4+n_] = *(const long long*)((TBL) +                           \
               ((((CB)*2+kk_)*16 + (w*4+n_))*64 + l)*8);                        \
       } } while (0)

#define MM8(AtC, Bc)                                                            \
  do { const char* A8_ = (const char*)(AtC);                                    \
       _Pragma("unroll")                                                        \
       for (int kk_ = 0; kk_ < 2; ++kk_) {                                      \
         long long a_[4];                                                       \
         _Pragma("unroll")                                                      \
         for (int m_ = 0; m_ < 4; ++m_) {                                       \
           int rm_ = 16*m_ + lr; int ch_ = (kk_*4+lq) ^ (rm_ & 6);              \
           a_[m_] = *(const long long*)(A8_ + rm_*64 + ch_*8);                  \
         }                                                                      \
         _Pragma("unroll")                                                      \
         for (int m_ = 0; m_ < 4; ++m_) {                                       \
           _Pragma("unroll")                                                    \
           for (int n_ = 0; n_ < 4; ++n_)                                       \
             acc[m_][n_] = __builtin_amdgcn_mfma_f32_16x16x32_fp8_fp8(          \
                 a_[m_], Bc[kk_*4+n_], acc[m_][n_], 0, 0, 0);                   \
         } } } while (0)

template <bool HEAD>
__global__ __launch_bounds__(256, 3)
void k_gemm(const unsigned char*  __restrict__ a8,     // [N,256] fp8 x / h1 (A op)
            const unsigned short* __restrict__ ares,   // [N,256] bf16 residual
            const unsigned char*  __restrict__ s8i,    // [N,256] fp8 sIn
            const unsigned char*  __restrict__ s8o,    // [N,256] fp8 sOut
            const unsigned char*  __restrict__ W8L,    // fp8 frag (W_loop)
            const unsigned char*  __restrict__ W8I,    // fp8 frag (W_in)
            const unsigned char*  __restrict__ W8O,    // fp8 frag (W_out)
            const float* __restrict__ bias,
            const float* __restrict__ resPtr,
            const unsigned short* __restrict__ WfMu,   // bf16 frag (HEAD)
            const float* __restrict__ mub,             // (HEAD)
            float* __restrict__ outF,                  // (HEAD)
            unsigned short* __restrict__ outB,         // (!HEAD)
            unsigned char* __restrict__ outB8,         // (!HEAD) fp8 h copy
            int N, int D)
{
    __shared__ unsigned char ldsb[HEAD ? 32768 : 16384];
    unsigned char* At0 = ldsb;
    unsigned char* At1 = ldsb + 4096;

    const int t = threadIdx.x;
    const int rBase = blockIdx.x * 64;

    const int w  = t >> 6;
    const int l  = t & 63;
    const int lr = l & 15;
    const int lq = l >> 4;

    // fp8 staging geometry (one 16B chunk / thread = 16 cols of a row)
    const int rf  = t >> 2;
    const int qf  = t & 3;
    const int wf8b = rf * 64 + (((2 * qf) ^ (rf & 6)) * 8);
    const size_t gf8 = (size_t)min(rBase + rf, N - 1) * 256 + qf * 16;

    f32x4 acc[4][4] = {};
    uint4 Ra, Rb, Rc, Rd, Re, Rf;
    long long B8a[8], B8b[8];

    // prologue: tiles 0..5 in flight; tile0 -> At0; B(step0)
    LD8(Ra, a8, 0); LD8(Rb, a8, 1); LD8(Rc, a8, 2); LD8(Rd, a8, 3);
    LD8(Re, s8i, 0); LD8(Rf, s8i, 1);
    PB8(B8a, W8L, 0);
    WR8(At0, Ra);
    FB;

    /*s0 */ WR8(At1, Rb); PB8(B8b, W8L, 1); MM8(At0, B8a); LD8(Ra, s8i, 2); FB;
    /*s1 */ WR8(At0, Rc); PB8(B8a, W8L, 2); MM8(At1, B8b); LD8(Rb, s8i, 3); FB;
    /*s2 */ WR8(At1, Rd); PB8(B8b, W8L, 3); MM8(At0, B8a); LD8(Rc, s8o, 0); FB;
    /*s3 */ WR8(At0, Re); PB8(B8a, W8I, 0); MM8(At1, B8b); LD8(Rd, s8o, 1); FB;
    /*s4 */ WR8(At1, Rf); PB8(B8b, W8I, 1); MM8(At0, B8a); LD8(Re, s8o, 2); FB;
    /*s5 */ WR8(At0, Ra); PB8(B8a, W8I, 2); MM8(At1, B8b); LD8(Rf, s8o, 3); FB;
    /*s6 */ WR8(At1, Rb); PB8(B8b, W8I, 3); MM8(At0, B8a); FB;
    /*s7 */ WR8(At0, Rc); PB8(B8a, W8O, 0); MM8(At1, B8b); FB;
    /*s8 */ WR8(At1, Rd); PB8(B8b, W8O, 1); MM8(At0, B8a); FB;
    /*s9 */ WR8(At0, Re); PB8(B8a, W8O, 2); MM8(At1, B8b); FB;
    /*s10*/ WR8(At1, Rf); PB8(B8b, W8O, 3); MM8(At0, B8a); FB;
    /*s11*/                                 MM8(At1, B8b); FB;

    const int rb4 = lq * 4;
    const float resv = resPtr[0];

    if (!HEAD) {
        // ---- coalesced epilogue: stage res*tanh(acc+bias) in LDS halves ----
        unsigned short* C = (unsigned short*)ldsb;   // 64 x 128 bf16 per half
        #pragma unroll
        for (int half = 0; half < 2; ++half) {
            if ((w >> 1) == half) {
                #pragma unroll
                for (int m = 0; m < 4; ++m) {
                    #pragma unroll
                    for (int i = 0; i < 4; ++i) {
                        int r6 = 16 * m + rb4 + i;
                        #pragma unroll
                        for (int n = 0; n < 4; ++n) {
                            int cH = (w & 1) * 64 + lr + 16 * n;
                            float v = acc[m][n][i] + bias[half * 128 + cH];
                            C[r6 * 128 + cH] = f2b(resv * ftanh(v));
                        }
                    }
                }
            }
            __syncthreads();
            #pragma unroll
            for (int ii = 0; ii < 4; ++ii) {
                int g   = ii * 256 + t;
                int r   = g >> 4;
                int cc  = g & 15;
                int row = rBase + r;
                if (row < N) {
                    bf16x8 sv = *(const bf16x8*)(&C[r * 128 + cc * 8]);
                    const unsigned short* ar = ares + (size_t)row * D + half * 128 + cc * 8;
                    uint4 av = *(const uint4*)ar;
                    unsigned aw[4] = { av.x, av.y, av.z, av.w };
                    unsigned ow[4];
                    float hv[8];
                    #pragma unroll
                    for (int p = 0; p < 4; ++p) {
                        float h0 = b2f((unsigned short)(aw[p] & 0xffff)) + b2f((unsigned short)sv[2 * p]);
                        float h1 = b2f((unsigned short)(aw[p] >> 16))    + b2f((unsigned short)sv[2 * p + 1]);
                        hv[2 * p] = h0; hv[2 * p + 1] = h1;
                        ow[p] = (unsigned)f2b(h0) | ((unsigned)f2b(h1) << 16);
                    }
                    *(uint4*)(outB + (size_t)row * D + half * 128 + cc * 8) =
                        make_uint4(ow[0], ow[1], ow[2], ow[3]);
                    uint2 q;
                    q.x = pk8_4(hv[0], hv[1], hv[2], hv[3]);
                    q.y = pk8_4(hv[4], hv[5], hv[6], hv[7]);
                    *(uint2*)(outB8 + (size_t)row * 256 + half * 128 + cc * 8) = q;
                }
            }
            __syncthreads();
        }
    } else {
        // ---- HEAD: h2 -> swizzled LDS bf16 tile, then out = h2 @ WfMu + mub ----
        unsigned short* lds = (unsigned short*)ldsb;   // 64 x 256 bf16
        #pragma unroll
        for (int m = 0; m < 4; ++m) {
            #pragma unroll
            for (int i = 0; i < 4; ++i) {
                int row = rBase + 16 * m + rb4 + i;
                if (row < N) {
                    size_t base = (size_t)row * D + w * 64 + lr;
                    int r6 = 16 * m + rb4 + i;
                    #pragma unroll
                    for (int n = 0; n < 4; ++n) {
                        int   c = w * 64 + lr + 16 * n;
                        float v = acc[m][n][i] + bias[c];
                        float h = b2f(ares[base + 16 * n]) + resv * ftanh(v);
                        lds[r6 * 256 + (c ^ ((r6 & 7) << 3))] = f2b(h);
                    }
                }
            }
        }
        __syncthreads();
        #pragma unroll
        for (int m = 0; m < 4; ++m) {
            #pragma unroll
            for (int n = 0; n < 4; ++n)
                acc[m][n] = (f32x4){0.f, 0.f, 0.f, 0.f};
        }

        #pragma unroll
        for (int s2 = 0; s2 < 4; ++s2) {
            #pragma unroll
            for (int kk = 0; kk < 2; ++kk) {
                const int kg = s2 * 2 + kk;
                bf16x8 a_[4], b_[4];
                #pragma unroll
                for (int m = 0; m < 4; ++m) {
                    int rm = 16 * m + lr;
                    int ch = (s2 * 8 + kk * 4 + lq) ^ (rm & 7);
                    a_[m] = *(const bf16x8*)(&lds[rm * 256 + ch * 8]);
                }
                #pragma unroll
                for (int n = 0; n < 4; ++n)
                    b_[n] = *(const bf16x8*)(WfMu + (((kg * 16 + (w * 4 + n)) * 64 + l) * 8));
                #pragma unroll
                for (int m = 0; m < 4; ++m) {
                    #pragma unroll
                    for (int n = 0; n < 4; ++n)
                        acc[m][n] = __builtin_amdgcn_mfma_f32_16x16x32_bf16(a_[m], b_[n], acc[m][n], 0, 0, 0);
                }
            }
        }

        __syncthreads();
        float* Cf = (float*)ldsb;                     // 64 x 128 f32 per half
        #pragma unroll
        for (int half = 0; half < 2; ++half) {
            if ((w >> 1) == half) {
                #pragma unroll
                for (int m = 0; m < 4; ++m) {
                    #pragma unroll
                    for (int i = 0; i < 4; ++i) {
                        int r6 = 16 * m + rb4 + i;
                        #pragma unroll
                        for (int n = 0; n < 4; ++n) {
                            int cH = (w & 1) * 64 + lr + 16 * n;
                            Cf[r6 * 128 + cH] = acc[m][n][i] + mub[half * 128 + cH];
                        }
                    }
                }
            }
            __syncthreads();
            #pragma unroll
            for (int ii = 0; ii < 8; ++ii) {
                int g   = ii * 256 + t;
                int r   = g >> 5;
                int cc  = g & 31;
                int row = rBase + r;
                if (row < N) {
                    *(float4*)(outF + (size_t)row * D + half * 128 + cc * 4) =
                        *(const float4*)(&Cf[r * 128 + cc * 4]);
                }
            }
            __syncthreads();
        }
    }
}

// ---------------------------------------------------------------------------

extern "C" void kernel_launch(void* const* d_in, const int* in_sizes, int n_in,
                              void* d_out, int out_size, void* d_ws, size_t ws_size,
                              hipStream_t stream)
{
    const float* emb  = (const float*)d_in[0];
    const int*   ei   = (const int*)  d_in[1];
    const int*   et   = (const int*)  d_in[2];
    const float* rel1 = (const float*)d_in[3];
    const float* Wi1  = (const float*)d_in[4];
    const float* Wo1  = (const float*)d_in[5];
    const float* Wl1  = (const float*)d_in[6];
    const float* b1   = (const float*)d_in[7];
    const float* rel2 = (const float*)d_in[8];
    const float* Wi2  = (const float*)d_in[9];
    const float* Wo2  = (const float*)d_in[10];
    const float* Wl2  = (const float*)d_in[11];
    const float* b2   = (const float*)d_in[12];
    const float* res  = (const float*)d_in[13];
    const float* muw  = (const float*)d_in[14];
    const float* mub  = (const float*)d_in[15];

    const int D = in_sizes[7];          // 256
    const int N = in_sizes[0] / D;      // 50000
    const int E = in_sizes[2];          // 320000
    const int R = in_sizes[3] / D;      // 400
    const int halfE = E / 2;
    const int* srcA = ei;
    const int* dstA = ei + E;
    const size_t DD = (size_t)D * D;

    char* ws = (char*)d_ws;
    size_t off = 0;
    auto alloc = [&](size_t bytes) -> char* {
        char* p = ws + off; off += (bytes + 255) & ~(size_t)255; return p;
    };
    const int nb1 = (N + 255) / 256;

    float*          norm   = (float*)          alloc((size_t)N * 4);
    int*            cnt    = (int*)            alloc((size_t)N * 4);
    int*            rowptr = (int*)            alloc((size_t)(N + 1) * 4);
    int*            cursor = (int*)            alloc((size_t)N * 4);
    int*            part   = (int*)            alloc((size_t)N * 4);
    int*            bsum   = (int*)            alloc(1024);
    unsigned*       erec   = (unsigned*)       alloc((size_t)E * 4);
    unsigned short* xb     = (unsigned short*) alloc((size_t)N * D * 2);
    unsigned short* h1b    = (unsigned short*) alloc((size_t)N * D * 2);
    unsigned char*  x8     = (unsigned char*)  alloc((size_t)N * D);
    unsigned char*  h18    = (unsigned char*)  alloc((size_t)N * D);
    unsigned char*  sIn8   = (unsigned char*)  alloc((size_t)N * D);
    unsigned char*  sOut8  = (unsigned char*)  alloc((size_t)N * D);
    unsigned short* r1b    = (unsigned short*) alloc((size_t)R * D * 2);
    unsigned short* r2b    = (unsigned short*) alloc((size_t)R * D * 2);
    unsigned char*  r18    = (unsigned char*)  alloc((size_t)R * D);
    unsigned char*  r28    = (unsigned char*)  alloc((size_t)R * D);
    unsigned short* fMu    = (unsigned short*) alloc(DD * 2);
    unsigned char*  f8All  = (unsigned char*)  alloc(6 * DD);
    if (off > ws_size) return;

    unsigned char* f8Wl1 = f8All;
    unsigned char* f8Wi1 = f8All + DD;
    unsigned char* f8Wo1 = f8All + 2 * DD;
    unsigned char* f8Wl2 = f8All + 3 * DD;
    unsigned char* f8Wi2 = f8All + 4 * DD;
    unsigned char* f8Wo2 = f8All + 5 * DD;

    // --- CSR + norm ---
    hipMemsetAsync(cnt, 0, (size_t)N * 4, stream);
    k_hist   <<<(E + 255) / 256, 256, 0, stream>>>(dstA, cnt, E);
    k_norm   <<<nb1, 256, 0, stream>>>(cnt, norm, N);
    k_scan1  <<<nb1, 256, 0, stream>>>(cnt, part, bsum, N);
    k_scan2  <<<1,   256, 0, stream>>>(bsum, nb1);
    k_scan3  <<<nb1, 256, 0, stream>>>(part, bsum, rowptr, cursor, N, E);
    k_scatter<<<(E + 255) / 256, 256, 0, stream>>>(srcA, dstA, et, cursor, erec, E, halfE);

    // --- dtype prep ---
    long nd4 = (long)N * D / 4, rd4 = (long)R * D / 4;
    long tot4 = nd4 + 2 * rd4;
    k_cvtx3<<<(int)((tot4 + 255) / 256), 256, 0, stream>>>(
        emb, xb, x8, nd4, rel1, r1b, r18, rd4, rel2, r2b, r28, rd4);
    k_wfrag1<<<(int)(DD / 256), 256, 0, stream>>>(muw, fMu);
    k_wfrag8<<<(int)(6 * DD / 1024), 256, 0, stream>>>(Wl1, Wi1, Wo1, Wl2, Wi2, Wo2, f8All);

    const int AB = (N + 3) / 4;
    const int NB = (N + 63) / 64;

    // --- layer 1 ---
    k_agg<<<AB, 256, 0, stream>>>(x8, r18, rowptr, erec, norm, sIn8, sOut8, N, D);
    k_gemm<false><<<NB, 256, 0, stream>>>(x8, xb, sIn8, sOut8, f8Wl1, f8Wi1, f8Wo1, b1, res,
                                          nullptr, nullptr, nullptr, h1b, h18, N, D);

    // --- layer 2 + head ---
    k_agg<<<AB, 256, 0, stream>>>(h18, r28, rowptr, erec, norm, sIn8, sOut8, N, D);
    k_gemm<true><<<NB, 256, 0, stream>>>(h18, h1b, sIn8, sOut8, f8Wl2, f8Wi2, f8Wo2, b2, res,
                                         fMu, mub, (float*)d_out, nullptr, nullptr, N, D);
}

// Round 18
// 203.328 us; speedup vs baseline: 1.5607x; 1.0102x over previous
//
#include <hip/hip_runtime.h>
#include <hip/hip_bf16.h>
#include <cstdint>
#include <cstddef>

// ---------------------------------------------------------------------------
// MGCN (2-layer relational GCN + linear head).  Converged configuration.
//
//   s_in[v]  = norm[v] * sum_{first-half edges,  dst=v} x[src]*rel[ty]
//   s_out[v] = norm[v] * sum_{second-half edges, dst=v} x[src]*rel[ty]
//   h        = x + res * tanh( x@W_loop + s_in@W_in + s_out@W_out + b )
//   out      = h2 @ mu_w + mu_b     (fused into layer-2 kernel)
//
// fp8 on all streaming paths: gather reads fp8 x/rel copies, s_in/s_out
// stored fp8, GEMM A-operands and W tables fp8 (mfma_f32_16x16x32_fp8_fp8),
// 64-row tiles, 12-step barrier pipeline, 6-deep register A prefetch.
// Residual path bf16; head GEMM bf16.  norm folded into scan1.
// ---------------------------------------------------------------------------

typedef short bf16x8 __attribute__((ext_vector_type(8)));
typedef float f32x4  __attribute__((ext_vector_type(4)));
typedef float f32x2  __attribute__((ext_vector_type(2)));

__device__ __forceinline__ float b2f(unsigned short u) {
    union { unsigned u32; float f; } c; c.u32 = ((unsigned)u) << 16; return c.f;
}
__device__ __forceinline__ unsigned short f2b(float f) {
    union { float f; unsigned u; } c; c.f = f;
    unsigned r = c.u + 0x7FFFu + ((c.u >> 16) & 1u);   // RNE
    return (unsigned short)(r >> 16);
}
__device__ __forceinline__ float ftanh(float x) {
    float e = __expf(2.0f * x);
    return 1.0f - __fdividef(2.0f, e + 1.0f);
}

// f32 -> fp8 e4m3fn (OCP), RNE, saturating (software fallback).
__device__ __forceinline__ unsigned char f2e4m3(float f) {
    unsigned u = __float_as_uint(f);
    unsigned s = (u >> 24) & 0x80u;
    unsigned a = u & 0x7fffffffu;
    if (a >= 0x43e00000u) return (unsigned char)(s | 0x7eu);
    if (a < 0x3c800000u) {
        float m = __uint_as_float(a) * 512.0f;
        int q = (int)rintf(m);
        if (q == 8) return (unsigned char)(s | 0x08u);
        return (unsigned char)(s | (unsigned)q);
    }
    unsigned m = a & 0x7fffffu;
    unsigned e = a >> 23;
    unsigned r = m + 0x7ffffu + ((m >> 20) & 1u);
    if (r >= 0x800000u) { e += 1; r -= 0x800000u; }
    if (e > 127u + 8u) return (unsigned char)(s | 0x7eu);
    return (unsigned char)(s | ((e - 127u + 7u) << 3) | (r >> 20));
}

__device__ __forceinline__ unsigned pk8_4(float a, float b, float c, float d) {
#if __has_builtin(__builtin_amdgcn_cvt_pk_fp8_f32)
    int v = 0;
    v = __builtin_amdgcn_cvt_pk_fp8_f32(a, b, v, false);
    v = __builtin_amdgcn_cvt_pk_fp8_f32(c, d, v, true);
    return (unsigned)v;
#else
    return (unsigned)f2e4m3(a) | ((unsigned)f2e4m3(b) << 8)
         | ((unsigned)f2e4m3(c) << 16) | ((unsigned)f2e4m3(d) << 24);
#endif
}

__device__ __forceinline__ void dec4(unsigned u, float* f) {
#if __has_builtin(__builtin_amdgcn_cvt_pk_f32_fp8)
    f32x2 lo = __builtin_amdgcn_cvt_pk_f32_fp8((int)u, false);
    f32x2 hi = __builtin_amdgcn_cvt_pk_f32_fp8((int)u, true);
    f[0] = lo[0]; f[1] = lo[1]; f[2] = hi[0]; f[3] = hi[1];
#else
    #pragma unroll
    for (int i = 0; i < 4; ++i) {
        unsigned b = (u >> (8 * i)) & 0xffu;
        unsigned em = b & 0x7fu;
        float mag;
        if (em >= 8u) mag = __uint_as_float((((em >> 3) + 120u) << 23) | ((em & 7u) << 20));
        else          mag = (float)em * 0.001953125f;
        f[i] = (b & 0x80u) ? -mag : mag;
    }
#endif
}

// ---- CSR construction ------------------------------------------------------

__global__ void k_hist(const int* __restrict__ dst, int* __restrict__ cnt, int E) {
    int i = blockIdx.x * blockDim.x + threadIdx.x;
    if (i < E) atomicAdd(&cnt[dst[i]], 1);
}

// scan stage 1 + norm computation (fused: cnt is already loaded here)
__global__ void k_scan1(const int* __restrict__ cnt, int* __restrict__ part,
                        int* __restrict__ bsum, float* __restrict__ norm, int N) {
    __shared__ int s[256];
    int i = blockIdx.x * 256 + threadIdx.x;
    int v = (i < N) ? cnt[i] : 0;
    if (i < N) norm[i] = 1.0f / fmaxf((float)v, 1.0f);
    s[threadIdx.x] = v; __syncthreads();
    #pragma unroll
    for (int o = 1; o < 256; o <<= 1) {
        int t = (threadIdx.x >= o) ? s[threadIdx.x - o] : 0;
        __syncthreads();
        s[threadIdx.x] += t;
        __syncthreads();
    }
    if (i < N) part[i] = s[threadIdx.x] - v;
    if (threadIdx.x == 255) bsum[blockIdx.x] = s[255];
}

__global__ void k_scan2(int* __restrict__ bsum, int nb) {
    __shared__ int s[256];
    int v = (threadIdx.x < nb) ? bsum[threadIdx.x] : 0;
    s[threadIdx.x] = v; __syncthreads();
    #pragma unroll
    for (int o = 1; o < 256; o <<= 1) {
        int t = (threadIdx.x >= o) ? s[threadIdx.x - o] : 0;
        __syncthreads();
        s[threadIdx.x] += t;
        __syncthreads();
    }
    if (threadIdx.x < nb) bsum[threadIdx.x] = s[threadIdx.x] - v;
}

__global__ void k_scan3(const int* __restrict__ part, const int* __restrict__ bsum,
                        int* __restrict__ rowptr, int* __restrict__ cursor, int N, int E) {
    int i = blockIdx.x * 256 + threadIdx.x;
    if (i < N) {
        int r = part[i] + bsum[blockIdx.x];
        rowptr[i] = r; cursor[i] = r;
    }
    if (i == 0) rowptr[N] = E;
}

__global__ void k_scatter(const int* __restrict__ src, const int* __restrict__ dst,
                          const int* __restrict__ et, int* __restrict__ cursor,
                          unsigned* __restrict__ erec, int E, int halfE) {
    int e = blockIdx.x * blockDim.x + threadIdx.x;
    if (e < E) {
        int d = dst[e];
        int pos = atomicAdd(&cursor[d], 1);
        unsigned rec = (unsigned)src[e] | ((unsigned)et[e] << 16)
                     | ((e >= halfE) ? 0x80000000u : 0u);
        erec[pos] = rec;
    }
}

// ---- dtype prep ------------------------------------------------------------

__global__ void k_cvtx3(const float* __restrict__ s0, unsigned short* __restrict__ d0,
                        unsigned char* __restrict__ e0, long n0,
                        const float* __restrict__ s1, unsigned short* __restrict__ d1,
                        unsigned char* __restrict__ e1, long n1,
                        const float* __restrict__ s2, unsigned short* __restrict__ d2,
                        unsigned char* __restrict__ e2, long n2) {
    long i = (long)blockIdx.x * blockDim.x + threadIdx.x;
    const float* s; unsigned short* d; unsigned char* e; long j = i;
    if (j < n0) { s = s0; d = d0; e = e0; }
    else {
        j -= n0;
        if (j < n1) { s = s1; d = d1; e = e1; }
        else { j -= n1; if (j >= n2) return; s = s2; d = d2; e = e2; }
    }
    float4 v = ((const float4*)s)[j];
    ushort4 o;
    o.x = f2b(v.x); o.y = f2b(v.y); o.z = f2b(v.z); o.w = f2b(v.w);
    ((ushort4*)d)[j] = o;
    ((unsigned*)e)[j] = pk8_4(v.x, v.y, v.z, v.w);
}

// bf16 fragment table: mu_w only
__global__ void k_wfrag1(const float* __restrict__ W, unsigned short* __restrict__ out) {
    int o = blockIdx.x * 256 + threadIdx.x;
    int j  = o & 7;
    int l  = (o >> 3) & 63;
    int nn = (o >> 9) & 15;
    int kg = o >> 13;
    int k = kg * 32 + (l >> 4) * 8 + j;
    int n = nn * 16 + (l & 15);
    out[o] = f2b(W[k * 256 + n]);
}

// fp8 fragment tables: Wl1, Wi1, Wo1, Wl2, Wi2, Wo2 (8-byte frags)
__global__ void k_wfrag8(const float* __restrict__ w0, const float* __restrict__ w1,
                         const float* __restrict__ w2, const float* __restrict__ w3,
                         const float* __restrict__ w4, const float* __restrict__ w5,
                         unsigned char* __restrict__ out) {
    int o = (blockIdx.x * 256 + threadIdx.x) * 4;
    int mi = o >> 16;
    int r  = o & 65535;
    const float* W = (mi == 0) ? w0 : (mi == 1) ? w1 : (mi == 2) ? w2 :
                     (mi == 3) ? w3 : (mi == 4) ? w4 : w5;
    int j0 = r & 7;
    int l  = (r >> 3) & 63;
    int nn = (r >> 9) & 15;
    int kg = r >> 13;
    int n  = nn * 16 + (l & 15);
    int kb = kg * 32 + (l >> 4) * 8 + j0;
    *(unsigned*)(out + o) = pk8_4(W[(kb + 0) * 256 + n], W[(kb + 1) * 256 + n],
                                  W[(kb + 2) * 256 + n], W[(kb + 3) * 256 + n]);
}

// ---- CSR gather aggregation: fp8 in/out, 4-edge pipeline -------------------

__global__ __launch_bounds__(256)
void k_agg(const unsigned char* __restrict__ x8, const unsigned char* __restrict__ rel8,
           const int* __restrict__ rowptr, const unsigned* __restrict__ erec,
           const float* __restrict__ norm,
           unsigned char* __restrict__ sIn8, unsigned char* __restrict__ sOut8,
           int N, int D)
{
    const int w = threadIdx.x >> 6, l = threadIdx.x & 63;
    const int v = blockIdx.x * 4 + w;
    if (v >= N) return;
    const int rs = rowptr[v], re = rowptr[v + 1];
    const float nm = norm[v];

    float ai0 = 0, ai1 = 0, ai2 = 0, ai3 = 0;
    float ao0 = 0, ao1 = 0, ao2 = 0, ao3 = 0;

    unsigned c0 = (rs     < re) ? erec[rs]     : 0u;
    unsigned c1 = (rs + 1 < re) ? erec[rs + 1] : 0u;
    unsigned c2 = (rs + 2 < re) ? erec[rs + 2] : 0u;
    unsigned c3 = (rs + 3 < re) ? erec[rs + 3] : 0u;
    int i = rs;
    while (i + 4 <= re) {
        unsigned m0 = (i + 4 < re) ? erec[i + 4] : 0u;
        unsigned m1 = (i + 5 < re) ? erec[i + 5] : 0u;
        unsigned m2 = (i + 6 < re) ? erec[i + 6] : 0u;
        unsigned m3 = (i + 7 < re) ? erec[i + 7] : 0u;
        unsigned xu0 = *(const unsigned*)(x8   + (size_t)(c0 & 0xffff) * 256 + l * 4);
        unsigned ru0 = *(const unsigned*)(rel8 + (size_t)((c0 >> 16) & 0x7fff) * 256 + l * 4);
        unsigned xu1 = *(const unsigned*)(x8   + (size_t)(c1 & 0xffff) * 256 + l * 4);
        unsigned ru1 = *(const unsigned*)(rel8 + (size_t)((c1 >> 16) & 0x7fff) * 256 + l * 4);
        unsigned xu2 = *(const unsigned*)(x8   + (size_t)(c2 & 0xffff) * 256 + l * 4);
        unsigned ru2 = *(const unsigned*)(rel8 + (size_t)((c2 >> 16) & 0x7fff) * 256 + l * 4);
        unsigned xu3 = *(const unsigned*)(x8   + (size_t)(c3 & 0xffff) * 256 + l * 4);
        unsigned ru3 = *(const unsigned*)(rel8 + (size_t)((c3 >> 16) & 0x7fff) * 256 + l * 4);
        float xf[4], rf[4];
        dec4(xu0, xf); dec4(ru0, rf);
        if (c0 >> 31) { ao0 += xf[0]*rf[0]; ao1 += xf[1]*rf[1]; ao2 += xf[2]*rf[2]; ao3 += xf[3]*rf[3]; }
        else          { ai0 += xf[0]*rf[0]; ai1 += xf[1]*rf[1]; ai2 += xf[2]*rf[2]; ai3 += xf[3]*rf[3]; }
        dec4(xu1, xf); dec4(ru1, rf);
        if (c1 >> 31) { ao0 += xf[0]*rf[0]; ao1 += xf[1]*rf[1]; ao2 += xf[2]*rf[2]; ao3 += xf[3]*rf[3]; }
        else          { ai0 += xf[0]*rf[0]; ai1 += xf[1]*rf[1]; ai2 += xf[2]*rf[2]; ai3 += xf[3]*rf[3]; }
        dec4(xu2, xf); dec4(ru2, rf);
        if (c2 >> 31) { ao0 += xf[0]*rf[0]; ao1 += xf[1]*rf[1]; ao2 += xf[2]*rf[2]; ao3 += xf[3]*rf[3]; }
        else          { ai0 += xf[0]*rf[0]; ai1 += xf[1]*rf[1]; ai2 += xf[2]*rf[2]; ai3 += xf[3]*rf[3]; }
        dec4(xu3, xf); dec4(ru3, rf);
        if (c3 >> 31) { ao0 += xf[0]*rf[0]; ao1 += xf[1]*rf[1]; ao2 += xf[2]*rf[2]; ao3 += xf[3]*rf[3]; }
        else          { ai0 += xf[0]*rf[0]; ai1 += xf[1]*rf[1]; ai2 += xf[2]*rf[2]; ai3 += xf[3]*rf[3]; }
        c0 = m0; c1 = m1; c2 = m2; c3 = m3; i += 4;
    }
    #pragma unroll
    for (int j = 0; j < 3; ++j) {
        if (i + j < re) {
            unsigned cur = (j == 0) ? c0 : (j == 1) ? c1 : c2;
            unsigned xu = *(const unsigned*)(x8   + (size_t)(cur & 0xffff) * 256 + l * 4);
            unsigned ru = *(const unsigned*)(rel8 + (size_t)((cur >> 16) & 0x7fff) * 256 + l * 4);
            float xf[4], rf[4];
            dec4(xu, xf); dec4(ru, rf);
            if (cur >> 31) { ao0 += xf[0]*rf[0]; ao1 += xf[1]*rf[1]; ao2 += xf[2]*rf[2]; ao3 += xf[3]*rf[3]; }
            else           { ai0 += xf[0]*rf[0]; ai1 += xf[1]*rf[1]; ai2 += xf[2]*rf[2]; ai3 += xf[3]*rf[3]; }
        }
    }

    *(unsigned*)(sIn8  + (size_t)v * 256 + l * 4) = pk8_4(ai0 * nm, ai1 * nm, ai2 * nm, ai3 * nm);
    *(unsigned*)(sOut8 + (size_t)v * 256 + l * 4) = pk8_4(ao0 * nm, ao1 * nm, ao2 * nm, ao3 * nm);
}

// ---- all-fp8 GEMM: 64-row tiles, uniform 12-step pipeline ------------------

#define FB  do { asm volatile("s_waitcnt lgkmcnt(0)" ::: "memory");             \
                 __builtin_amdgcn_sched_barrier(0);                             \
                 __builtin_amdgcn_s_barrier();                                  \
                 __builtin_amdgcn_sched_barrier(0); } while (0)

#define WR8(AtN, R0)     do { *(uint4*)((AtN) + wf8b) = R0; } while (0)
#define LD8(R0, SRC, CB) do { R0 = *(const uint4*)((SRC) + gf8 + (CB)*64); } while (0)

#define PB8(Bn, TBL, CB)                                                        \
  do { _Pragma("unroll")                                                        \
       for (int kk_ = 0; kk_ < 2; ++kk_) {                                      \
         _Pragma("unroll")                                                      \
         for (int n_ = 0; n_ < 4; ++n_)                                         \
           Bn[kk_*4+n_] = *(const long long*)((TBL) +                           \
               ((((CB)*2+kk_)*16 + (w*4+n_))*64 + l)*8);                        \
       } } while (0)

#define MM8(AtC, Bc)                                                            \
  do { const char* A8_ = (const char*)(AtC);                                    \
       _Pragma("unroll")                                                        \
       for (int kk_ = 0; kk_ < 2; ++kk_) {                                      \
         long long a_[4];                                                       \
         _Pragma("unroll")                                                      \
         for (int m_ = 0; m_ < 4; ++m_) {                                       \
           int rm_ = 16*m_ + lr; int ch_ = (kk_*4+lq) ^ (rm_ & 6);              \
           a_[m_] = *(const long long*)(A8_ + rm_*64 + ch_*8);                  \
         }                                                                      \
         _Pragma("unroll")                                                      \
         for (int m_ = 0; m_ < 4; ++m_) {                                       \
           _Pragma("unroll")                                                    \
           for (int n_ = 0; n_ < 4; ++n_)                                       \
             acc[m_][n_] = __builtin_amdgcn_mfma_f32_16x16x32_fp8_fp8(          \
                 a_[m_], Bc[kk_*4+n_], acc[m_][n_], 0, 0, 0);                   \
         } } } while (0)

template <bool HEAD>
__global__ __launch_bounds__(256, 3)
void k_gemm(const unsigned char*  __restrict__ a8,     // [N,256] fp8 x / h1 (A op)
            const unsigned short* __restrict__ ares,   // [N,256] bf16 residual
            const unsigned char*  __restrict__ s8i,    // [N,256] fp8 sIn
            const unsigned char*  __restrict__ s8o,    // [N,256] fp8 sOut
            const unsigned char*  __restrict__ W8L,    // fp8 frag (W_loop)
            const unsigned char*  __restrict__ W8I,    // fp8 frag (W_in)
            const unsigned char*  __restrict__ W8O,    // fp8 frag (W_out)
            const float* __restrict__ bias,
            const float* __restrict__ resPtr,
            const unsigned short* __restrict__ WfMu,   // bf16 frag (HEAD)
            const float* __restrict__ mub,             // (HEAD)
            float* __restrict__ outF,                  // (HEAD)
            unsigned short* __restrict__ outB,         // (!HEAD)
            unsigned char* __restrict__ outB8,         // (!HEAD) fp8 h copy
            int N, int D)
{
    __shared__ unsigned char ldsb[HEAD ? 32768 : 16384];
    unsigned char* At0 = ldsb;
    unsigned char* At1 = ldsb + 4096;

    const int t = threadIdx.x;
    const int rBase = blockIdx.x * 64;

    const int w  = t >> 6;
    const int l  = t & 63;
    const int lr = l & 15;
    const int lq = l >> 4;

    // fp8 staging geometry (one 16B chunk / thread = 16 cols of a row)
    const int rf  = t >> 2;
    const int qf  = t & 3;
    const int wf8b = rf * 64 + (((2 * qf) ^ (rf & 6)) * 8);
    const size_t gf8 = (size_t)min(rBase + rf, N - 1) * 256 + qf * 16;

    f32x4 acc[4][4] = {};
    uint4 Ra, Rb, Rc, Rd, Re, Rf;
    long long B8a[8], B8b[8];

    // prologue: tiles 0..5 in flight; tile0 -> At0; B(step0)
    LD8(Ra, a8, 0); LD8(Rb, a8, 1); LD8(Rc, a8, 2); LD8(Rd, a8, 3);
    LD8(Re, s8i, 0); LD8(Rf, s8i, 1);
    PB8(B8a, W8L, 0);
    WR8(At0, Ra);
    FB;

    /*s0 */ WR8(At1, Rb); PB8(B8b, W8L, 1); MM8(At0, B8a); LD8(Ra, s8i, 2); FB;
    /*s1 */ WR8(At0, Rc); PB8(B8a, W8L, 2); MM8(At1, B8b); LD8(Rb, s8i, 3); FB;
    /*s2 */ WR8(At1, Rd); PB8(B8b, W8L, 3); MM8(At0, B8a); LD8(Rc, s8o, 0); FB;
    /*s3 */ WR8(At0, Re); PB8(B8a, W8I, 0); MM8(At1, B8b); LD8(Rd, s8o, 1); FB;
    /*s4 */ WR8(At1, Rf); PB8(B8b, W8I, 1); MM8(At0, B8a); LD8(Re, s8o, 2); FB;
    /*s5 */ WR8(At0, Ra); PB8(B8a, W8I, 2); MM8(At1, B8b); LD8(Rf, s8o, 3); FB;
    /*s6 */ WR8(At1, Rb); PB8(B8b, W8I, 3); MM8(At0, B8a); FB;
    /*s7 */ WR8(At0, Rc); PB8(B8a, W8O, 0); MM8(At1, B8b); FB;
    /*s8 */ WR8(At1, Rd); PB8(B8b, W8O, 1); MM8(At0, B8a); FB;
    /*s9 */ WR8(At0, Re); PB8(B8a, W8O, 2); MM8(At1, B8b); FB;
    /*s10*/ WR8(At1, Rf); PB8(B8b, W8O, 3); MM8(At0, B8a); FB;
    /*s11*/                                 MM8(At1, B8b); FB;

    const int rb4 = lq * 4;
    const float resv = resPtr[0];

    if (!HEAD) {
        // ---- coalesced epilogue: stage res*tanh(acc+bias) in LDS halves ----
        unsigned short* C = (unsigned short*)ldsb;   // 64 x 128 bf16 per half
        #pragma unroll
        for (int half = 0; half < 2; ++half) {
            if ((w >> 1) == half) {
                #pragma unroll
                for (int m = 0; m < 4; ++m) {
                    #pragma unroll
                    for (int i = 0; i < 4; ++i) {
                        int r6 = 16 * m + rb4 + i;
                        #pragma unroll
                        for (int n = 0; n < 4; ++n) {
                            int cH = (w & 1) * 64 + lr + 16 * n;
                            float v = acc[m][n][i] + bias[half * 128 + cH];
                            C[r6 * 128 + cH] = f2b(resv * ftanh(v));
                        }
                    }
                }
            }
            __syncthreads();
            #pragma unroll
            for (int ii = 0; ii < 4; ++ii) {
                int g   = ii * 256 + t;
                int r   = g >> 4;
                int cc  = g & 15;
                int row = rBase + r;
                if (row < N) {
                    bf16x8 sv = *(const bf16x8*)(&C[r * 128 + cc * 8]);
                    const unsigned short* ar = ares + (size_t)row * D + half * 128 + cc * 8;
                    uint4 av = *(const uint4*)ar;
                    unsigned aw[4] = { av.x, av.y, av.z, av.w };
                    unsigned ow[4];
                    float hv[8];
                    #pragma unroll
                    for (int p = 0; p < 4; ++p) {
                        float h0 = b2f((unsigned short)(aw[p] & 0xffff)) + b2f((unsigned short)sv[2 * p]);
                        float h1 = b2f((unsigned short)(aw[p] >> 16))    + b2f((unsigned short)sv[2 * p + 1]);
                        hv[2 * p] = h0; hv[2 * p + 1] = h1;
                        ow[p] = (unsigned)f2b(h0) | ((unsigned)f2b(h1) << 16);
                    }
                    *(uint4*)(outB + (size_t)row * D + half * 128 + cc * 8) =
                        make_uint4(ow[0], ow[1], ow[2], ow[3]);
                    uint2 q;
                    q.x = pk8_4(hv[0], hv[1], hv[2], hv[3]);
                    q.y = pk8_4(hv[4], hv[5], hv[6], hv[7]);
                    *(uint2*)(outB8 + (size_t)row * 256 + half * 128 + cc * 8) = q;
                }
            }
            __syncthreads();
        }
    } else {
        // ---- HEAD: h2 -> swizzled LDS bf16 tile, then out = h2 @ WfMu + mub ----
        unsigned short* lds = (unsigned short*)ldsb;   // 64 x 256 bf16
        #pragma unroll
        for (int m = 0; m < 4; ++m) {
            #pragma unroll
            for (int i = 0; i < 4; ++i) {
                int row = rBase + 16 * m + rb4 + i;
                if (row < N) {
                    size_t base = (size_t)row * D + w * 64 + lr;
                    int r6 = 16 * m + rb4 + i;
                    #pragma unroll
                    for (int n = 0; n < 4; ++n) {
                        int   c = w * 64 + lr + 16 * n;
                        float v = acc[m][n][i] + bias[c];
                        float h = b2f(ares[base + 16 * n]) + resv * ftanh(v);
                        lds[r6 * 256 + (c ^ ((r6 & 7) << 3))] = f2b(h);
                    }
                }
            }
        }
        __syncthreads();
        #pragma unroll
        for (int m = 0; m < 4; ++m) {
            #pragma unroll
            for (int n = 0; n < 4; ++n)
                acc[m][n] = (f32x4){0.f, 0.f, 0.f, 0.f};
        }

        #pragma unroll
        for (int s2 = 0; s2 < 4; ++s2) {
            #pragma unroll
            for (int kk = 0; kk < 2; ++kk) {
                const int kg = s2 * 2 + kk;
                bf16x8 a_[4], b_[4];
                #pragma unroll
                for (int m = 0; m < 4; ++m) {
                    int rm = 16 * m + lr;
                    int ch = (s2 * 8 + kk * 4 + lq) ^ (rm & 7);
                    a_[m] = *(const bf16x8*)(&lds[rm * 256 + ch * 8]);
                }
                #pragma unroll
                for (int n = 0; n < 4; ++n)
                    b_[n] = *(const bf16x8*)(WfMu + (((kg * 16 + (w * 4 + n)) * 64 + l) * 8));
                #pragma unroll
                for (int m = 0; m < 4; ++m) {
                    #pragma unroll
                    for (int n = 0; n < 4; ++n)
                        acc[m][n] = __builtin_amdgcn_mfma_f32_16x16x32_bf16(a_[m], b_[n], acc[m][n], 0, 0, 0);
                }
            }
        }

        __syncthreads();
        float* Cf = (float*)ldsb;                     // 64 x 128 f32 per half
        #pragma unroll
        for (int half = 0; half < 2; ++half) {
            if ((w >> 1) == half) {
                #pragma unroll
                for (int m = 0; m < 4; ++m) {
                    #pragma unroll
                    for (int i = 0; i < 4; ++i) {
                        int r6 = 16 * m + rb4 + i;
                        #pragma unroll
                        for (int n = 0; n < 4; ++n) {
                            int cH = (w & 1) * 64 + lr + 16 * n;
                            Cf[r6 * 128 + cH] = acc[m][n][i] + mub[half * 128 + cH];
                        }
                    }
                }
            }
            __syncthreads();
            #pragma unroll
            for (int ii = 0; ii < 8; ++ii) {
                int g   = ii * 256 + t;
                int r   = g >> 5;
                int cc  = g & 31;
                int row = rBase + r;
                if (row < N) {
                    *(float4*)(outF + (size_t)row * D + half * 128 + cc * 4) =
                        *(const float4*)(&Cf[r * 128 + cc * 4]);
                }
            }
            __syncthreads();
        }
    }
}

// ---------------------------------------------------------------------------

extern "C" void kernel_launch(void* const* d_in, const int* in_sizes, int n_in,
                              void* d_out, int out_size, void* d_ws, size_t ws_size,
                              hipStream_t stream)
{
    const float* emb  = (const float*)d_in[0];
    const int*   ei   = (const int*)  d_in[1];
    const int*   et   = (const int*)  d_in[2];
    const float* rel1 = (const float*)d_in[3];
    const float* Wi1  = (const float*)d_in[4];
    const float* Wo1  = (const float*)d_in[5];
    const float* Wl1  = (const float*)d_in[6];
    const float* b1   = (const float*)d_in[7];
    const float* rel2 = (const float*)d_in[8];
    const float* Wi2  = (const float*)d_in[9];
    const float* Wo2  = (const float*)d_in[10];
    const float* Wl2  = (const float*)d_in[11];
    const float* b2   = (const float*)d_in[12];
    const float* res  = (const float*)d_in[13];
    const float* muw  = (const float*)d_in[14];
    const float* mub  = (const float*)d_in[15];

    const int D = in_sizes[7];          // 256
    const int N = in_sizes[0] / D;      // 50000
    const int E = in_sizes[2];          // 320000
    const int R = in_sizes[3] / D;      // 400
    const int halfE = E / 2;
    const int* srcA = ei;
    const int* dstA = ei + E;
    const size_t DD = (size_t)D * D;

    char* ws = (char*)d_ws;
    size_t off = 0;
    auto alloc = [&](size_t bytes) -> char* {
        char* p = ws + off; off += (bytes + 255) & ~(size_t)255; return p;
    };
    const int nb1 = (N + 255) / 256;

    float*          norm   = (float*)          alloc((size_t)N * 4);
    int*            cnt    = (int*)            alloc((size_t)N * 4);
    int*            rowptr = (int*)            alloc((size_t)(N + 1) * 4);
    int*            cursor = (int*)            alloc((size_t)N * 4);
    int*            part   = (int*)            alloc((size_t)N * 4);
    int*            bsum   = (int*)            alloc(1024);
    unsigned*       erec   = (unsigned*)       alloc((size_t)E * 4);
    unsigned short* xb     = (unsigned short*) alloc((size_t)N * D * 2);
    unsigned short* h1b    = (unsigned short*) alloc((size_t)N * D * 2);
    unsigned char*  x8     = (unsigned char*)  alloc((size_t)N * D);
    unsigned char*  h18    = (unsigned char*)  alloc((size_t)N * D);
    unsigned char*  sIn8   = (unsigned char*)  alloc((size_t)N * D);
    unsigned char*  sOut8  = (unsigned char*)  alloc((size_t)N * D);
    unsigned short* r1b    = (unsigned short*) alloc((size_t)R * D * 2);
    unsigned short* r2b    = (unsigned short*) alloc((size_t)R * D * 2);
    unsigned char*  r18    = (unsigned char*)  alloc((size_t)R * D);
    unsigned char*  r28    = (unsigned char*)  alloc((size_t)R * D);
    unsigned short* fMu    = (unsigned short*) alloc(DD * 2);
    unsigned char*  f8All  = (unsigned char*)  alloc(6 * DD);
    if (off > ws_size) return;

    unsigned char* f8Wl1 = f8All;
    unsigned char* f8Wi1 = f8All + DD;
    unsigned char* f8Wo1 = f8All + 2 * DD;
    unsigned char* f8Wl2 = f8All + 3 * DD;
    unsigned char* f8Wi2 = f8All + 4 * DD;
    unsigned char* f8Wo2 = f8All + 5 * DD;

    // --- CSR + norm ---
    hipMemsetAsync(cnt, 0, (size_t)N * 4, stream);
    k_hist   <<<(E + 255) / 256, 256, 0, stream>>>(dstA, cnt, E);
    k_scan1  <<<nb1, 256, 0, stream>>>(cnt, part, bsum, norm, N);
    k_scan2  <<<1,   256, 0, stream>>>(bsum, nb1);
    k_scan3  <<<nb1, 256, 0, stream>>>(part, bsum, rowptr, cursor, N, E);
    k_scatter<<<(E + 255) / 256, 256, 0, stream>>>(srcA, dstA, et, cursor, erec, E, halfE);

    // --- dtype prep ---
    long nd4 = (long)N * D / 4, rd4 = (long)R * D / 4;
    long tot4 = nd4 + 2 * rd4;
    k_cvtx3<<<(int)((tot4 + 255) / 256), 256, 0, stream>>>(
        emb, xb, x8, nd4, rel1, r1b, r18, rd4, rel2, r2b, r28, rd4);
    k_wfrag1<<<(int)(DD / 256), 256, 0, stream>>>(muw, fMu);
    k_wfrag8<<<(int)(6 * DD / 1024), 256, 0, stream>>>(Wl1, Wi1, Wo1, Wl2, Wi2, Wo2, f8All);

    const int AB = (N + 3) / 4;
    const int NB = (N + 63) / 64;

    // --- layer 1 ---
    k_agg<<<AB, 256, 0, stream>>>(x8, r18, rowptr, erec, norm, sIn8, sOut8, N, D);
    k_gemm<false><<<NB, 256, 0, stream>>>(x8, xb, sIn8, sOut8, f8Wl1, f8Wi1, f8Wo1, b1, res,
                                          nullptr, nullptr, nullptr, h1b, h18, N, D);

    // --- layer 2 + head ---
    k_agg<<<AB, 256, 0, stream>>>(h18, r28, rowptr, erec, norm, sIn8, sOut8, N, D);
    k_gemm<true><<<NB, 256, 0, stream>>>(h18, h1b, sIn8, sOut8, f8Wl2, f8Wi2, f8Wo2, b2, res,
                                         fMu, mub, (float*)d_out, nullptr, nullptr, N, D);
}